// Round 4
// baseline (201.659 us; speedup 1.0000x reference)
//
#include <hip/hip_runtime.h>

typedef __attribute__((ext_vector_type(4)))  float f32x4;
typedef __attribute__((ext_vector_type(16))) float f32x16;
typedef __attribute__((ext_vector_type(8)))  short short8;

#define DD 256          // feature dim
#define CC 512          // num classes
#define LDP 264         // padded LDS row stride (bf16 elems): 528B, 16B-aligned, <=4-way conflict

__device__ __forceinline__ unsigned short f2bf(float f) {
    union { float f; unsigned u; } x; x.f = f;
    unsigned r = x.u + 0x7FFFu + ((x.u >> 16) & 1u);   // RNE
    return (unsigned short)(r >> 16);
}

__device__ __forceinline__ f32x4 ntload4(const f32x4* p) {
    return __builtin_nontemporal_load(p);
}

// ---------------- K1: per-class segment sum of normalized support rows ----------------
// grid = 1024: (class, half). Depth-4 pipelined gather: four matched-row loads in flight,
// four interleaved shuffle-reduce chains. All gather branches are wave-uniform (ballot mask).
__global__ __launch_bounds__(256) void class_sum_kernel(
    const f32x4* __restrict__ S, const int* __restrict__ labels,
    float* __restrict__ sums2, float* __restrict__ counts2, int N_s)
{
    const int c = blockIdx.x >> 1, half = blockIdx.x & 1;
    const int w = threadIdx.x >> 6, l = threadIdx.x & 63;
    const int seg  = N_s >> 3;
    const int base = half * (N_s >> 1) + w * seg;
    const int4* lab4 = (const int4*)(labels + base);
    const int iters = seg >> 8;

    float ax = 0.f, ay = 0.f, az = 0.f, aw = 0.f;
    int cnt = 0;

    int4 pf0 = lab4[l];
    int4 pf1 = (iters > 1) ? lab4[64 + l] : make_int4(-1, -1, -1, -1);

    for (int it = 0; it < iters; ++it) {
        int4 lv = pf0;
        pf0 = pf1;
        pf1 = (it + 2 < iters) ? lab4[(it + 2) * 64 + l] : make_int4(-1, -1, -1, -1);
        #pragma unroll
        for (int s = 0; s < 4; ++s) {
            int lab = (s == 0) ? lv.x : (s == 1) ? lv.y : (s == 2) ? lv.z : lv.w;
            unsigned long long m = __ballot(lab == c);
            cnt += __popcll(m);
            while (m) {
                int p0 = __ffsll((long long)m) - 1; m &= m - 1;
                int p1 = -1, p2 = -1, p3 = -1;
                if (m) { p1 = __ffsll((long long)m) - 1; m &= m - 1;
                    if (m) { p2 = __ffsll((long long)m) - 1; m &= m - 1;
                        if (m) { p3 = __ffsll((long long)m) - 1; m &= m - 1; } } }
                f32x4 v0 = ntload4(&S[(size_t)(base + (it * 64 + p0) * 4 + s) * 64 + l]);
                f32x4 v1 = {0,0,0,0}, v2 = {0,0,0,0}, v3 = {0,0,0,0};
                if (p1 >= 0) v1 = ntload4(&S[(size_t)(base + (it * 64 + p1) * 4 + s) * 64 + l]);
                if (p2 >= 0) v2 = ntload4(&S[(size_t)(base + (it * 64 + p2) * 4 + s) * 64 + l]);
                if (p3 >= 0) v3 = ntload4(&S[(size_t)(base + (it * 64 + p3) * 4 + s) * 64 + l]);
                float s0 = v0[0]*v0[0] + v0[1]*v0[1] + v0[2]*v0[2] + v0[3]*v0[3];
                float s1 = v1[0]*v1[0] + v1[1]*v1[1] + v1[2]*v1[2] + v1[3]*v1[3];
                float s2 = v2[0]*v2[0] + v2[1]*v2[1] + v2[2]*v2[2] + v2[3]*v2[3];
                float s3 = v3[0]*v3[0] + v3[1]*v3[1] + v3[2]*v3[2] + v3[3]*v3[3];
                #pragma unroll
                for (int off = 32; off; off >>= 1) {
                    s0 += __shfl_xor(s0, off);
                    s1 += __shfl_xor(s1, off);
                    s2 += __shfl_xor(s2, off);
                    s3 += __shfl_xor(s3, off);
                }
                float i0 = 1.0f / fmaxf(sqrtf(s0), 1e-8f);
                ax += v0[0]*i0; ay += v0[1]*i0; az += v0[2]*i0; aw += v0[3]*i0;
                if (p1 >= 0) { float i1 = 1.0f / fmaxf(sqrtf(s1), 1e-8f);
                    ax += v1[0]*i1; ay += v1[1]*i1; az += v1[2]*i1; aw += v1[3]*i1; }
                if (p2 >= 0) { float i2 = 1.0f / fmaxf(sqrtf(s2), 1e-8f);
                    ax += v2[0]*i2; ay += v2[1]*i2; az += v2[2]*i2; aw += v2[3]*i2; }
                if (p3 >= 0) { float i3 = 1.0f / fmaxf(sqrtf(s3), 1e-8f);
                    ax += v3[0]*i3; ay += v3[1]*i3; az += v3[2]*i3; aw += v3[3]*i3; }
            }
        }
    }

    __shared__ float lred[4][DD];
    __shared__ float lcnt[4];
    lred[w][4*l+0] = ax; lred[w][4*l+1] = ay; lred[w][4*l+2] = az; lred[w][4*l+3] = aw;
    if (l == 0) lcnt[w] = (float)cnt;
    __syncthreads();
    int t = threadIdx.x;
    sums2[(size_t)(half * CC + c) * DD + t] = lred[0][t] + lred[1][t] + lred[2][t] + lred[3][t];
    if (t == 0) counts2[half * CC + c] = lcnt[0] + lcnt[1] + lcnt[2] + lcnt[3];
}

// ---------------- K2: centroid partials (8 blocks, no atomics) ----------------
__global__ __launch_bounds__(256) void centroid_kernel(
    const float* __restrict__ sums2, float* __restrict__ gpart)
{
    const int d = threadIdx.x, b = blockIdx.x;
    float s = 0.f;
    for (int j = 0; j < 64; ++j) {
        int c = b * 64 + j;
        s += sums2[(size_t)c * DD + d] + sums2[(size_t)(CC + c) * DD + d];
    }
    gpart[b * DD + d] = s;
}

// ---------------- K3: prototypes (shrink + renormalize) -> bf16 P, + unique_classes ----
__global__ __launch_bounds__(256) void proto_kernel(
    const float* __restrict__ sums2, const float* __restrict__ counts2,
    const float* __restrict__ gpart, const float* __restrict__ proto_shrink,
    unsigned short* __restrict__ Pbf, float* __restrict__ outUC, int N_s)
{
    const int c = blockIdx.x, d = threadIdx.x;
    float ps = proto_shrink[0];
    float ab = 1.0f / (1.0f + __expf(-ps));
    ab = fminf(fmaxf(ab, 0.0f), 0.4f);

    float sum  = sums2[(size_t)c * DD + d] + sums2[(size_t)(CC + c) * DD + d];
    float cntv = fmaxf(counts2[c] + counts2[CC + c], 1.0f);
    float g = 0.f;
    #pragma unroll
    for (int b = 0; b < 8; ++b) g += gpart[b * DD + d];
    g /= (float)N_s;

    float mean  = sum / cntv;
    float alpha = ab / sqrtf(cntv);
    float p = (1.0f - alpha) * mean + alpha * g;

    float ss = p * p;
    #pragma unroll
    for (int off = 32; off; off >>= 1) ss += __shfl_xor(ss, off);
    __shared__ float l4[4];
    if ((threadIdx.x & 63) == 0) l4[threadIdx.x >> 6] = ss;
    __syncthreads();
    ss = l4[0] + l4[1] + l4[2] + l4[3];
    float inv = 1.0f / fmaxf(sqrtf(ss), 1e-8f);
    Pbf[(size_t)c * DD + d] = f2bf(p * inv);
    if (d == 0) outUC[c] = (float)c;
}

// ---------------- K4: logits = normalize(q) @ P^T * scale ----------------
// M-tile 256, grid 512 (exactly 2 blocks/CU). Wave owns 64 rows as TWO row-blocks in regs
// (A loaded direct from global, raw bf16). Each LDS B-read feeds 2 MFMAs (halved LDS traffic).
// Row normalization applied at the epilogue via shuffled 1/||q|| * scale factors.
__global__ __launch_bounds__(256, 2) void logits_kernel(
    const float4* __restrict__ Q, const unsigned short* __restrict__ Pbf,
    const float* __restrict__ logit_scale, float* __restrict__ out)
{
    __shared__ unsigned short Blds[2][64 * LDP];   // 2 x 33792 B

    const int t  = threadIdx.x;
    const int w  = t >> 6, l = t & 63;
    const int lr = l & 31, lh = l >> 5;
    const int m0 = blockIdx.x * 256;
    const int br = t >> 2, bq = t & 3;
    const unsigned short* Pb = Pbf + (size_t)br * DD + bq * 64;

    // prefetch B chunk 0 (latency hidden under A load/convert)
    short8 breg[8];
    #pragma unroll
    for (int i = 0; i < 8; ++i) breg[i] = *(const short8*)(Pb + i * 8);

    // ---- A: two 32-row blocks per wave, direct global load -> bf16 frags + row ssq ----
    short8 a0[16], a1[16];
    float inv0, inv1;
    #pragma unroll
    for (int rb = 0; rb < 2; ++rb) {
        const int row = m0 + 64 * w + rb * 32 + lr;
        const float4* qr = Q + (size_t)row * 64 + lh * 2;
        float ss = 0.f;
        #pragma unroll
        for (int k = 0; k < 16; ++k) {
            float4 x = qr[k * 4];
            float4 y = qr[k * 4 + 1];
            ss += x.x*x.x + x.y*x.y + x.z*x.z + x.w*x.w
                + y.x*y.x + y.y*y.y + y.z*y.z + y.w*y.w;
            short8 f;
            f[0] = (short)f2bf(x.x); f[1] = (short)f2bf(x.y);
            f[2] = (short)f2bf(x.z); f[3] = (short)f2bf(x.w);
            f[4] = (short)f2bf(y.x); f[5] = (short)f2bf(y.y);
            f[6] = (short)f2bf(y.z); f[7] = (short)f2bf(y.w);
            if (rb == 0) a0[k] = f; else a1[k] = f;
        }
        ss += __shfl_xor(ss, 32);
        float inv = 1.0f / fmaxf(sqrtf(ss), 1e-8f);
        if (rb == 0) inv0 = inv; else inv1 = inv;
    }

    // epilogue scale factors: sv[rb][r] = (1/||q_row||)*scale for out row (r&3)+8*(r>>2)+4*lh
    const float s = fminf(fmaxf(logit_scale[0], 1.0f), 100.0f);
    float sv0[16], sv1[16];
    #pragma unroll
    for (int r = 0; r < 16; ++r) {
        int src = (r & 3) + 8 * (r >> 2) + 4 * lh;
        sv0[r] = __shfl(inv0, src) * s;
        sv1[r] = __shfl(inv1, src) * s;
    }

    // write B0 to LDS, prefetch B1
    {
        unsigned short* dst = &Blds[0][br * LDP + bq * 64];
        #pragma unroll
        for (int i = 0; i < 8; ++i) *(short8*)(dst + i * 8) = breg[i];
        const unsigned short* src = Pb + (size_t)64 * DD;
        #pragma unroll
        for (int i = 0; i < 8; ++i) breg[i] = *(const short8*)(src + i * 8);
    }
    __builtin_amdgcn_sched_barrier(0);
    asm volatile("s_waitcnt lgkmcnt(0)");
    __builtin_amdgcn_sched_barrier(0);
    __builtin_amdgcn_s_barrier();                // B0 ready
    __builtin_amdgcn_sched_barrier(0);

    for (int c0 = 0; c0 < 8; ++c0) {
        // stage chunk c0+1 (counted vmcnt on breg handled by compiler)
        if (c0 < 7) {
            unsigned short* dst = &Blds[(c0 + 1) & 1][br * LDP + bq * 64];
            #pragma unroll
            for (int i = 0; i < 8; ++i) *(short8*)(dst + i * 8) = breg[i];
        }
        // prefetch chunk c0+2
        if (c0 < 6) {
            const unsigned short* src = Pb + (size_t)(c0 + 2) * 64 * DD;
            #pragma unroll
            for (int i = 0; i < 8; ++i) breg[i] = *(const short8*)(src + i * 8);
        }
        // compute from Blds[c0&1]
        #pragma unroll
        for (int nf = 0; nf < 2; ++nf) {
            f32x16 acc0, acc1;
            #pragma unroll
            for (int r = 0; r < 16; ++r) { acc0[r] = 0.f; acc1[r] = 0.f; }
            const unsigned short* bbase = &Blds[c0 & 1][(nf * 32 + lr) * LDP + lh * 8];
            __builtin_amdgcn_s_setprio(1);
            #pragma unroll
            for (int k = 0; k < 16; ++k) {
                short8 b = *(const short8*)(bbase + k * 16);
                acc0 = __builtin_amdgcn_mfma_f32_32x32x16_bf16(a0[k], b, acc0, 0, 0, 0);
                acc1 = __builtin_amdgcn_mfma_f32_32x32x16_bf16(a1[k], b, acc1, 0, 0, 0);
            }
            __builtin_amdgcn_s_setprio(0);
            const int col   = c0 * 64 + nf * 32 + lr;
            const int rbase = m0 + 64 * w + 4 * lh;
            #pragma unroll
            for (int r = 0; r < 16; ++r) {
                int row = rbase + (r & 3) + 8 * (r >> 2);
                __builtin_nontemporal_store(acc0[r] * sv0[r], &out[(size_t)row * CC + col]);
                __builtin_nontemporal_store(acc1[r] * sv1[r], &out[(size_t)(row + 32) * CC + col]);
            }
        }
        if (c0 < 7) {
            __builtin_amdgcn_sched_barrier(0);
            asm volatile("s_waitcnt lgkmcnt(0)");    // my ds_write + ds_read retired
            __builtin_amdgcn_sched_barrier(0);
            __builtin_amdgcn_s_barrier();            // next buffer ready / old free
            __builtin_amdgcn_sched_barrier(0);
        }
    }
}

extern "C" void kernel_launch(void* const* d_in, const int* in_sizes, int n_in,
                              void* d_out, int out_size, void* d_ws, size_t ws_size,
                              hipStream_t stream) {
    const float* S      = (const float*)d_in[0];
    const int*   labels = (const int*)d_in[1];
    const float* Qf     = (const float*)d_in[2];
    const float* lscale = (const float*)d_in[3];
    const float* pshr   = (const float*)d_in[4];

    const int N_s = in_sizes[0] / DD;     // 65536
    const int N_q = in_sizes[2] / DD;     // 131072

    float* sums2         = (float*)d_ws;                                   // 2*512*256*4
    float* counts2       = (float*)((char*)d_ws + 1048576);                // 2*512*4
    float* gpart         = (float*)((char*)d_ws + 1052672);                // 8*256*4
    unsigned short* Pbf  = (unsigned short*)((char*)d_ws + 1060864);       // 512*256*2

    float* out   = (float*)d_out;
    float* outUC = out + (size_t)N_q * CC;

    class_sum_kernel<<<2 * CC, 256, 0, stream>>>((const f32x4*)S, labels, sums2, counts2, N_s);
    centroid_kernel<<<8, 256, 0, stream>>>(sums2, gpart);
    proto_kernel<<<CC, 256, 0, stream>>>(sums2, counts2, gpart, pshr, Pbf, outUC, N_s);
    logits_kernel<<<N_q / 256, 256, 0, stream>>>((const float4*)Qf, Pbf, lscale, out);
}

// Round 5
// 111.588 us; speedup vs baseline: 1.8072x; 1.8072x over previous
//
#include <hip/hip_runtime.h>

typedef __attribute__((ext_vector_type(4)))  float f32x4;
typedef __attribute__((ext_vector_type(16))) float f32x16;
typedef __attribute__((ext_vector_type(8)))  short short8;

#define DD 256          // feature dim
#define CC 512          // num classes
#define LDP2 264        // padded LDS row stride (bf16 elems) for A chunks: 528B

__device__ __forceinline__ unsigned short f2bf(float f) {
    union { float f; unsigned u; } x; x.f = f;
    unsigned r = x.u + 0x7FFFu + ((x.u >> 16) & 1u);   // RNE
    return (unsigned short)(r >> 16);
}

__device__ __forceinline__ f32x4 ntload4(const f32x4* p) {
    return __builtin_nontemporal_load(p);
}

// ---------------- K1: per-class segment sum of normalized support rows ----------------
__global__ __launch_bounds__(256) void class_sum_kernel(
    const f32x4* __restrict__ S, const int* __restrict__ labels,
    float* __restrict__ sums2, float* __restrict__ counts2, int N_s)
{
    const int c = blockIdx.x >> 1, half = blockIdx.x & 1;
    const int w = threadIdx.x >> 6, l = threadIdx.x & 63;
    const int seg  = N_s >> 3;
    const int base = half * (N_s >> 1) + w * seg;
    const int4* lab4 = (const int4*)(labels + base);
    const int iters = seg >> 8;

    float ax = 0.f, ay = 0.f, az = 0.f, aw = 0.f;
    int cnt = 0;

    int4 pf0 = lab4[l];
    int4 pf1 = (iters > 1) ? lab4[64 + l] : make_int4(-1, -1, -1, -1);

    for (int it = 0; it < iters; ++it) {
        int4 lv = pf0;
        pf0 = pf1;
        pf1 = (it + 2 < iters) ? lab4[(it + 2) * 64 + l] : make_int4(-1, -1, -1, -1);
        #pragma unroll
        for (int s = 0; s < 4; ++s) {
            int lab = (s == 0) ? lv.x : (s == 1) ? lv.y : (s == 2) ? lv.z : lv.w;
            unsigned long long m = __ballot(lab == c);
            cnt += __popcll(m);
            while (m) {
                int p0 = __ffsll((long long)m) - 1; m &= m - 1;
                int p1 = -1, p2 = -1, p3 = -1;
                if (m) { p1 = __ffsll((long long)m) - 1; m &= m - 1;
                    if (m) { p2 = __ffsll((long long)m) - 1; m &= m - 1;
                        if (m) { p3 = __ffsll((long long)m) - 1; m &= m - 1; } } }
                f32x4 v0 = ntload4(&S[(size_t)(base + (it * 64 + p0) * 4 + s) * 64 + l]);
                f32x4 v1 = {0,0,0,0}, v2 = {0,0,0,0}, v3 = {0,0,0,0};
                if (p1 >= 0) v1 = ntload4(&S[(size_t)(base + (it * 64 + p1) * 4 + s) * 64 + l]);
                if (p2 >= 0) v2 = ntload4(&S[(size_t)(base + (it * 64 + p2) * 4 + s) * 64 + l]);
                if (p3 >= 0) v3 = ntload4(&S[(size_t)(base + (it * 64 + p3) * 4 + s) * 64 + l]);
                float s0 = v0[0]*v0[0] + v0[1]*v0[1] + v0[2]*v0[2] + v0[3]*v0[3];
                float s1 = v1[0]*v1[0] + v1[1]*v1[1] + v1[2]*v1[2] + v1[3]*v1[3];
                float s2 = v2[0]*v2[0] + v2[1]*v2[1] + v2[2]*v2[2] + v2[3]*v2[3];
                float s3 = v3[0]*v3[0] + v3[1]*v3[1] + v3[2]*v3[2] + v3[3]*v3[3];
                #pragma unroll
                for (int off = 32; off; off >>= 1) {
                    s0 += __shfl_xor(s0, off);
                    s1 += __shfl_xor(s1, off);
                    s2 += __shfl_xor(s2, off);
                    s3 += __shfl_xor(s3, off);
                }
                float i0 = 1.0f / fmaxf(sqrtf(s0), 1e-8f);
                ax += v0[0]*i0; ay += v0[1]*i0; az += v0[2]*i0; aw += v0[3]*i0;
                if (p1 >= 0) { float i1 = 1.0f / fmaxf(sqrtf(s1), 1e-8f);
                    ax += v1[0]*i1; ay += v1[1]*i1; az += v1[2]*i1; aw += v1[3]*i1; }
                if (p2 >= 0) { float i2 = 1.0f / fmaxf(sqrtf(s2), 1e-8f);
                    ax += v2[0]*i2; ay += v2[1]*i2; az += v2[2]*i2; aw += v2[3]*i2; }
                if (p3 >= 0) { float i3 = 1.0f / fmaxf(sqrtf(s3), 1e-8f);
                    ax += v3[0]*i3; ay += v3[1]*i3; az += v3[2]*i3; aw += v3[3]*i3; }
            }
        }
    }

    __shared__ float lred[4][DD];
    __shared__ float lcnt[4];
    lred[w][4*l+0] = ax; lred[w][4*l+1] = ay; lred[w][4*l+2] = az; lred[w][4*l+3] = aw;
    if (l == 0) lcnt[w] = (float)cnt;
    __syncthreads();
    int t = threadIdx.x;
    sums2[(size_t)(half * CC + c) * DD + t] = lred[0][t] + lred[1][t] + lred[2][t] + lred[3][t];
    if (t == 0) counts2[half * CC + c] = lcnt[0] + lcnt[1] + lcnt[2] + lcnt[3];
}

// ---------------- K2: centroid partials (8 blocks, no atomics) ----------------
__global__ __launch_bounds__(256) void centroid_kernel(
    const float* __restrict__ sums2, float* __restrict__ gpart)
{
    const int d = threadIdx.x, b = blockIdx.x;
    float s = 0.f;
    for (int j = 0; j < 64; ++j) {
        int c = b * 64 + j;
        s += sums2[(size_t)c * DD + d] + sums2[(size_t)(CC + c) * DD + d];
    }
    gpart[b * DD + d] = s;
}

// ---------------- K3: prototypes -> bf16 Pt in MFMA B-FRAGMENT layout ----------------
// Pt element for (class c, dim d):
//   CT=c>>5, KT=d>>4, lane=(c&31)+32*((d>>3)&1), e=d&7
//   Pt[((CT*16+KT)*64+lane)*8+e]
// so in logits, lane l loads 16B at ((CT*16+k)*64+l)*8 -> coalesced dwordx4, frag-ready.
__global__ __launch_bounds__(256) void proto_kernel(
    const float* __restrict__ sums2, const float* __restrict__ counts2,
    const float* __restrict__ gpart, const float* __restrict__ proto_shrink,
    unsigned short* __restrict__ Pt, float* __restrict__ outUC, int N_s)
{
    const int c = blockIdx.x, d = threadIdx.x;
    float ps = proto_shrink[0];
    float ab = 1.0f / (1.0f + __expf(-ps));
    ab = fminf(fmaxf(ab, 0.0f), 0.4f);

    float sum  = sums2[(size_t)c * DD + d] + sums2[(size_t)(CC + c) * DD + d];
    float cntv = fmaxf(counts2[c] + counts2[CC + c], 1.0f);
    float g = 0.f;
    #pragma unroll
    for (int b = 0; b < 8; ++b) g += gpart[b * DD + d];
    g /= (float)N_s;

    float mean  = sum / cntv;
    float alpha = ab / sqrtf(cntv);
    float p = (1.0f - alpha) * mean + alpha * g;

    float ss = p * p;
    #pragma unroll
    for (int off = 32; off; off >>= 1) ss += __shfl_xor(ss, off);
    __shared__ float l4[4];
    if ((threadIdx.x & 63) == 0) l4[threadIdx.x >> 6] = ss;
    __syncthreads();
    ss = l4[0] + l4[1] + l4[2] + l4[3];
    float inv = 1.0f / fmaxf(sqrtf(ss), 1e-8f);

    const int CT = c >> 5, KT = d >> 4;
    const int lane = (c & 31) + 32 * ((d >> 3) & 1);
    const int e = d & 7;
    Pt[(size_t)(((CT * 16 + KT) * 64 + lane)) * 8 + e] = f2bf(p * inv);
    if (d == 0) outUC[c] = (float)c;
}

// ---------------- K4: logits = normalize(q) @ P^T * scale ----------------
// Persistent: grid 256 (1 block/CU), 512 threads (8 waves). Wave w holds ALL B-frags for
// its 64 columns in registers (b[32] = 128 VGPR, one-time coalesced load from Pt).
// Q streams through a double-buffered 32-row LDS chunk (normalized bf16) -> HBM stays
// continuously busy with Q-reads + logit-stores; no serial A prologue per tile.
__global__ __launch_bounds__(512, 2) void logits_kernel(
    const float4* __restrict__ Q, const unsigned short* __restrict__ Pt,
    const float* __restrict__ logit_scale, float* __restrict__ out, int nch)
{
    __shared__ unsigned short A[2][32 * LDP2];   // 2 x 16.9 KB

    const int t  = threadIdx.x;
    const int w  = t >> 6, l = t & 63;
    const int lr = l & 31, lh = l >> 5;
    const int m0 = blockIdx.x * nch * 32;        // this block's row range
    const int sr = t >> 4, sc = t & 15;          // staging: 16 threads/row, 16 floats each

    const float s = fminf(fmaxf(logit_scale[0], 1.0f), 100.0f);

    // ---- B prologue: wave w's 64 columns, frag-ready coalesced loads ----
    short8 b[32];
    #pragma unroll
    for (int ct = 0; ct < 2; ++ct)
        #pragma unroll
        for (int k = 0; k < 16; ++k)
            b[ct * 16 + k] = *(const short8*)(Pt + (size_t)(((2 * w + ct) * 16 + k) * 64 + l) * 8);

    // ---- staging pipeline regs: v holds the NEXT chunk's 16 floats/thread ----
    float4 v[4];
    const float4* qbase = Q + ((size_t)(m0 + sr) * DD + sc * 16) / 4;

    // load chunk 0
    #pragma unroll
    for (int i = 0; i < 4; ++i) v[i] = qbase[i];
    // stage chunk 0 -> A[0]
    {
        float ss = 0.f;
        #pragma unroll
        for (int i = 0; i < 4; ++i)
            ss += v[i].x*v[i].x + v[i].y*v[i].y + v[i].z*v[i].z + v[i].w*v[i].w;
        ss += __shfl_xor(ss, 1); ss += __shfl_xor(ss, 2);
        ss += __shfl_xor(ss, 4); ss += __shfl_xor(ss, 8);
        float inv = 1.0f / fmaxf(sqrtf(ss), 1e-8f);
        unsigned short* dst = &A[0][sr * LDP2 + sc * 16];
        #pragma unroll
        for (int h = 0; h < 2; ++h) {
            short8 pk;
            float4 x = v[2*h], y = v[2*h+1];
            pk[0] = (short)f2bf(x.x*inv); pk[1] = (short)f2bf(x.y*inv);
            pk[2] = (short)f2bf(x.z*inv); pk[3] = (short)f2bf(x.w*inv);
            pk[4] = (short)f2bf(y.x*inv); pk[5] = (short)f2bf(y.y*inv);
            pk[6] = (short)f2bf(y.z*inv); pk[7] = (short)f2bf(y.w*inv);
            *(short8*)(dst + h * 8) = pk;
        }
    }
    // issue chunk 1 loads
    if (nch > 1) {
        const float4* src = qbase + 32 * (DD / 4);
        #pragma unroll
        for (int i = 0; i < 4; ++i) v[i] = src[i];
    }
    __builtin_amdgcn_sched_barrier(0);
    asm volatile("s_waitcnt lgkmcnt(0)");
    __builtin_amdgcn_sched_barrier(0);
    __builtin_amdgcn_s_barrier();                // A[0] ready
    __builtin_amdgcn_sched_barrier(0);

    for (int c = 0; c < nch; ++c) {
        const int p = c & 1;
        // ---- compute chunk c from A[p] + reg-resident B ----
        f32x16 acc0, acc1;
        #pragma unroll
        for (int r = 0; r < 16; ++r) { acc0[r] = 0.f; acc1[r] = 0.f; }
        const unsigned short* ab = &A[p][lr * LDP2 + lh * 8];
        __builtin_amdgcn_s_setprio(1);
        #pragma unroll
        for (int k = 0; k < 16; ++k) {
            short8 af = *(const short8*)(ab + k * 16);
            acc0 = __builtin_amdgcn_mfma_f32_32x32x16_bf16(af, b[k],      acc0, 0, 0, 0);
            acc1 = __builtin_amdgcn_mfma_f32_32x32x16_bf16(af, b[k + 16], acc1, 0, 0, 0);
        }
        __builtin_amdgcn_s_setprio(0);
        {
            const int col  = 64 * w + lr;
            const int rb   = m0 + c * 32 + 4 * lh;
            #pragma unroll
            for (int r = 0; r < 16; ++r) {
                int row = rb + (r & 3) + 8 * (r >> 2);
                __builtin_nontemporal_store(acc0[r] * s, &out[(size_t)row * CC + col]);
                __builtin_nontemporal_store(acc1[r] * s, &out[(size_t)row * CC + col + 32]);
            }
        }
        __builtin_amdgcn_sched_barrier(0);
        asm volatile("s_waitcnt lgkmcnt(0)");
        __builtin_amdgcn_sched_barrier(0);
        __builtin_amdgcn_s_barrier();            // all waves done reading A[p]
        __builtin_amdgcn_sched_barrier(0);

        if (c + 1 < nch) {
            // ---- stage chunk c+1 (v) -> A[p^1] ----
            float ss = 0.f;
            #pragma unroll
            for (int i = 0; i < 4; ++i)
                ss += v[i].x*v[i].x + v[i].y*v[i].y + v[i].z*v[i].z + v[i].w*v[i].w;
            ss += __shfl_xor(ss, 1); ss += __shfl_xor(ss, 2);
            ss += __shfl_xor(ss, 4); ss += __shfl_xor(ss, 8);
            float inv = 1.0f / fmaxf(sqrtf(ss), 1e-8f);
            unsigned short* dst = &A[p ^ 1][sr * LDP2 + sc * 16];
            #pragma unroll
            for (int h = 0; h < 2; ++h) {
                short8 pk;
                float4 x = v[2*h], y = v[2*h+1];
                pk[0] = (short)f2bf(x.x*inv); pk[1] = (short)f2bf(x.y*inv);
                pk[2] = (short)f2bf(x.z*inv); pk[3] = (short)f2bf(x.w*inv);
                pk[4] = (short)f2bf(y.x*inv); pk[5] = (short)f2bf(y.y*inv);
                pk[6] = (short)f2bf(y.z*inv); pk[7] = (short)f2bf(y.w*inv);
                *(short8*)(dst + h * 8) = pk;
            }
            // issue chunk c+2 loads
            if (c + 2 < nch) {
                const float4* src = qbase + (size_t)(c + 2) * 32 * (DD / 4);
                #pragma unroll
                for (int i = 0; i < 4; ++i) v[i] = src[i];
            }
            __builtin_amdgcn_sched_barrier(0);
            asm volatile("s_waitcnt lgkmcnt(0)");
            __builtin_amdgcn_sched_barrier(0);
            __builtin_amdgcn_s_barrier();        // A[p^1] ready
            __builtin_amdgcn_sched_barrier(0);
        }
    }
}

extern "C" void kernel_launch(void* const* d_in, const int* in_sizes, int n_in,
                              void* d_out, int out_size, void* d_ws, size_t ws_size,
                              hipStream_t stream) {
    const float* S      = (const float*)d_in[0];
    const int*   labels = (const int*)d_in[1];
    const float* Qf     = (const float*)d_in[2];
    const float* lscale = (const float*)d_in[3];
    const float* pshr   = (const float*)d_in[4];

    const int N_s = in_sizes[0] / DD;     // 65536
    const int N_q = in_sizes[2] / DD;     // 131072

    float* sums2         = (float*)d_ws;                                   // 2*512*256*4
    float* counts2       = (float*)((char*)d_ws + 1048576);                // 2*512*4
    float* gpart         = (float*)((char*)d_ws + 1052672);                // 8*256*4
    unsigned short* Pt   = (unsigned short*)((char*)d_ws + 1060864);       // 512*256*2

    float* out   = (float*)d_out;
    float* outUC = out + (size_t)N_q * CC;

    const int nblk = 256;
    const int nch  = N_q / (nblk * 32);   // 16

    class_sum_kernel<<<2 * CC, 256, 0, stream>>>((const f32x4*)S, labels, sums2, counts2, N_s);
    centroid_kernel<<<8, 256, 0, stream>>>(sums2, gpart);
    proto_kernel<<<CC, 256, 0, stream>>>(sums2, counts2, gpart, pshr, Pt, outUC, N_s);
    logits_kernel<<<nblk, 512, 0, stream>>>((const float4*)Qf, Pt, lscale, out, nch);
}

// Round 6
// 110.614 us; speedup vs baseline: 1.8231x; 1.0088x over previous
//
#include <hip/hip_runtime.h>

typedef __attribute__((ext_vector_type(4)))  float f32x4;
typedef __attribute__((ext_vector_type(16))) float f32x16;
typedef __attribute__((ext_vector_type(8)))  short short8;

#define DD 256          // feature dim
#define CC 512          // num classes
#define LDP2 264        // padded LDS row stride (bf16 elems): 528B

__device__ __forceinline__ unsigned short f2bf(float f) {
    union { float f; unsigned u; } x; x.f = f;
    unsigned r = x.u + 0x7FFFu + ((x.u >> 16) & 1u);   // RNE
    return (unsigned short)(r >> 16);
}

__device__ __forceinline__ f32x4 ntload4(const f32x4* p) {
    return __builtin_nontemporal_load(p);
}

// ---------------- K1: per-class segment sum of normalized support rows ----------------
__global__ __launch_bounds__(256) void class_sum_kernel(
    const f32x4* __restrict__ S, const int* __restrict__ labels,
    float* __restrict__ sums2, float* __restrict__ counts2, int N_s)
{
    const int c = blockIdx.x >> 1, half = blockIdx.x & 1;
    const int w = threadIdx.x >> 6, l = threadIdx.x & 63;
    const int seg  = N_s >> 3;
    const int base = half * (N_s >> 1) + w * seg;
    const int4* lab4 = (const int4*)(labels + base);
    const int iters = seg >> 8;

    float ax = 0.f, ay = 0.f, az = 0.f, aw = 0.f;
    int cnt = 0;

    int4 pf0 = lab4[l];
    int4 pf1 = (iters > 1) ? lab4[64 + l] : make_int4(-1, -1, -1, -1);

    for (int it = 0; it < iters; ++it) {
        int4 lv = pf0;
        pf0 = pf1;
        pf1 = (it + 2 < iters) ? lab4[(it + 2) * 64 + l] : make_int4(-1, -1, -1, -1);
        #pragma unroll
        for (int s = 0; s < 4; ++s) {
            int lab = (s == 0) ? lv.x : (s == 1) ? lv.y : (s == 2) ? lv.z : lv.w;
            unsigned long long m = __ballot(lab == c);
            cnt += __popcll(m);
            while (m) {
                int p0 = __ffsll((long long)m) - 1; m &= m - 1;
                int p1 = -1, p2 = -1, p3 = -1;
                if (m) { p1 = __ffsll((long long)m) - 1; m &= m - 1;
                    if (m) { p2 = __ffsll((long long)m) - 1; m &= m - 1;
                        if (m) { p3 = __ffsll((long long)m) - 1; m &= m - 1; } } }
                f32x4 v0 = ntload4(&S[(size_t)(base + (it * 64 + p0) * 4 + s) * 64 + l]);
                f32x4 v1 = {0,0,0,0}, v2 = {0,0,0,0}, v3 = {0,0,0,0};
                if (p1 >= 0) v1 = ntload4(&S[(size_t)(base + (it * 64 + p1) * 4 + s) * 64 + l]);
                if (p2 >= 0) v2 = ntload4(&S[(size_t)(base + (it * 64 + p2) * 4 + s) * 64 + l]);
                if (p3 >= 0) v3 = ntload4(&S[(size_t)(base + (it * 64 + p3) * 4 + s) * 64 + l]);
                float s0 = v0[0]*v0[0] + v0[1]*v0[1] + v0[2]*v0[2] + v0[3]*v0[3];
                float s1 = v1[0]*v1[0] + v1[1]*v1[1] + v1[2]*v1[2] + v1[3]*v1[3];
                float s2 = v2[0]*v2[0] + v2[1]*v2[1] + v2[2]*v2[2] + v2[3]*v2[3];
                float s3 = v3[0]*v3[0] + v3[1]*v3[1] + v3[2]*v3[2] + v3[3]*v3[3];
                #pragma unroll
                for (int off = 32; off; off >>= 1) {
                    s0 += __shfl_xor(s0, off);
                    s1 += __shfl_xor(s1, off);
                    s2 += __shfl_xor(s2, off);
                    s3 += __shfl_xor(s3, off);
                }
                float i0 = 1.0f / fmaxf(sqrtf(s0), 1e-8f);
                ax += v0[0]*i0; ay += v0[1]*i0; az += v0[2]*i0; aw += v0[3]*i0;
                if (p1 >= 0) { float i1 = 1.0f / fmaxf(sqrtf(s1), 1e-8f);
                    ax += v1[0]*i1; ay += v1[1]*i1; az += v1[2]*i1; aw += v1[3]*i1; }
                if (p2 >= 0) { float i2 = 1.0f / fmaxf(sqrtf(s2), 1e-8f);
                    ax += v2[0]*i2; ay += v2[1]*i2; az += v2[2]*i2; aw += v2[3]*i2; }
                if (p3 >= 0) { float i3 = 1.0f / fmaxf(sqrtf(s3), 1e-8f);
                    ax += v3[0]*i3; ay += v3[1]*i3; az += v3[2]*i3; aw += v3[3]*i3; }
            }
        }
    }

    __shared__ float lred[4][DD];
    __shared__ float lcnt[4];
    lred[w][4*l+0] = ax; lred[w][4*l+1] = ay; lred[w][4*l+2] = az; lred[w][4*l+3] = aw;
    if (l == 0) lcnt[w] = (float)cnt;
    __syncthreads();
    int t = threadIdx.x;
    sums2[(size_t)(half * CC + c) * DD + t] = lred[0][t] + lred[1][t] + lred[2][t] + lred[3][t];
    if (t == 0) counts2[half * CC + c] = lcnt[0] + lcnt[1] + lcnt[2] + lcnt[3];
}

// ---------------- K2: centroid partials (8 blocks, no atomics) ----------------
__global__ __launch_bounds__(256) void centroid_kernel(
    const float* __restrict__ sums2, float* __restrict__ gpart)
{
    const int d = threadIdx.x, b = blockIdx.x;
    float s = 0.f;
    for (int j = 0; j < 64; ++j) {
        int c = b * 64 + j;
        s += sums2[(size_t)c * DD + d] + sums2[(size_t)(CC + c) * DD + d];
    }
    gpart[b * DD + d] = s;
}

// ---------------- K3: prototypes -> bf16 Pt in MFMA B-frag layout, SCALE FOLDED IN ----
// Pt element for (class c, dim d):
//   CT=c>>5, KT=d>>4, lane=(c&31)+32*((d>>3)&1), e=d&7 -> Pt[((CT*16+KT)*64+lane)*8+e]
__global__ __launch_bounds__(256) void proto_kernel(
    const float* __restrict__ sums2, const float* __restrict__ counts2,
    const float* __restrict__ gpart, const float* __restrict__ proto_shrink,
    const float* __restrict__ logit_scale,
    unsigned short* __restrict__ Pt, float* __restrict__ outUC, int N_s)
{
    const int c = blockIdx.x, d = threadIdx.x;
    float ps = proto_shrink[0];
    float ab = 1.0f / (1.0f + __expf(-ps));
    ab = fminf(fmaxf(ab, 0.0f), 0.4f);
    const float sc = fminf(fmaxf(logit_scale[0], 1.0f), 100.0f);

    float sum  = sums2[(size_t)c * DD + d] + sums2[(size_t)(CC + c) * DD + d];
    float cntv = fmaxf(counts2[c] + counts2[CC + c], 1.0f);
    float g = 0.f;
    #pragma unroll
    for (int b = 0; b < 8; ++b) g += gpart[b * DD + d];
    g /= (float)N_s;

    float mean  = sum / cntv;
    float alpha = ab / sqrtf(cntv);
    float p = (1.0f - alpha) * mean + alpha * g;

    float ss = p * p;
    #pragma unroll
    for (int off = 32; off; off >>= 1) ss += __shfl_xor(ss, off);
    __shared__ float l4[4];
    if ((threadIdx.x & 63) == 0) l4[threadIdx.x >> 6] = ss;
    __syncthreads();
    ss = l4[0] + l4[1] + l4[2] + l4[3];
    float inv = sc / fmaxf(sqrtf(ss), 1e-8f);    // logit scale folded into prototype

    const int CT = c >> 5, KT = d >> 4;
    const int lane = (c & 31) + 32 * ((d >> 3) & 1);
    const int e = d & 7;
    Pt[(size_t)(((CT * 16 + KT) * 64 + lane)) * 8 + e] = f2bf(p * inv);
    if (d == 0) outUC[c] = (float)c;
}

// ---------------- K4: logits = normalize(q) @ (P*s)^T ----------------
// Persistent: grid 256 (1 block/CU), 512 threads (8 waves). Wave w holds ALL B-frags for
// its 64 columns in regs (b[32]=128 VGPR). Q streams through double-buffered 64-row LDS
// chunks with a SINGLE barrier per chunk: stage(c+1) writes A[(c+1)&1] while compute(c)
// reads A[c&1] in the same phase (disjoint buffers); the barrier at end of iter c-1
// already separates stage(c+1) from compute(c-1)'s reads. MFMA/VALU/DS/VMEM co-schedule.
__global__ __launch_bounds__(512, 2) void logits_kernel(
    const float4* __restrict__ Q, const unsigned short* __restrict__ Pt,
    float* __restrict__ out, int nch)
{
    __shared__ unsigned short A[2][64 * LDP2];   // 2 x 33.8 KB

    const int t  = threadIdx.x;
    const int w  = t >> 6, l = t & 63;
    const int lr = l & 31, lh = l >> 5;
    const int m0 = blockIdx.x * nch * 64;        // this block's row range
    const int sr = t >> 3, sc = t & 7;           // staging: 8 threads/row, 32 floats each

    // ---- B prologue: wave w's 64 columns, frag-ready coalesced loads ----
    short8 b[32];
    #pragma unroll
    for (int ct = 0; ct < 2; ++ct)
        #pragma unroll
        for (int k = 0; k < 16; ++k)
            b[ct * 16 + k] = *(const short8*)(Pt + (size_t)(((2 * w + ct) * 16 + k) * 64 + l) * 8);

    const float4* qbase = Q + (size_t)(m0 + sr) * 64 + sc * 8;

    float4 v[8];
    #pragma unroll
    for (int i = 0; i < 8; ++i) v[i] = qbase[i];            // chunk 0

    // stage chunk 0 -> A[0]
    {
        float ss = 0.f;
        #pragma unroll
        for (int i = 0; i < 8; ++i)
            ss += v[i].x*v[i].x + v[i].y*v[i].y + v[i].z*v[i].z + v[i].w*v[i].w;
        ss += __shfl_xor(ss, 1); ss += __shfl_xor(ss, 2); ss += __shfl_xor(ss, 4);
        float inv = 1.0f / fmaxf(sqrtf(ss), 1e-8f);
        unsigned short* dst = &A[0][sr * LDP2 + sc * 32];
        #pragma unroll
        for (int h = 0; h < 4; ++h) {
            short8 pk;
            float4 x = v[2*h], y = v[2*h+1];
            pk[0] = (short)f2bf(x.x*inv); pk[1] = (short)f2bf(x.y*inv);
            pk[2] = (short)f2bf(x.z*inv); pk[3] = (short)f2bf(x.w*inv);
            pk[4] = (short)f2bf(y.x*inv); pk[5] = (short)f2bf(y.y*inv);
            pk[6] = (short)f2bf(y.z*inv); pk[7] = (short)f2bf(y.w*inv);
            *(short8*)(dst + h * 8) = pk;
        }
    }
    if (nch > 1) {                                          // chunk 1 loads in flight
        const float4* src = qbase + (size_t)64 * 64;
        #pragma unroll
        for (int i = 0; i < 8; ++i) v[i] = src[i];
    }
    __builtin_amdgcn_sched_barrier(0);
    asm volatile("s_waitcnt lgkmcnt(0)");
    __builtin_amdgcn_sched_barrier(0);
    __builtin_amdgcn_s_barrier();                // A[0] ready
    __builtin_amdgcn_sched_barrier(0);

    for (int c = 0; c < nch; ++c) {
        const int p = c & 1;

        // ---- stage chunk c+1 -> A[p^1] (same phase as compute; disjoint buffer) ----
        if (c + 1 < nch) {
            float ss = 0.f;
            #pragma unroll
            for (int i = 0; i < 8; ++i)
                ss += v[i].x*v[i].x + v[i].y*v[i].y + v[i].z*v[i].z + v[i].w*v[i].w;
            ss += __shfl_xor(ss, 1); ss += __shfl_xor(ss, 2); ss += __shfl_xor(ss, 4);
            float inv = 1.0f / fmaxf(sqrtf(ss), 1e-8f);
            unsigned short* dst = &A[p ^ 1][sr * LDP2 + sc * 32];
            #pragma unroll
            for (int h = 0; h < 4; ++h) {
                short8 pk;
                float4 x = v[2*h], y = v[2*h+1];
                pk[0] = (short)f2bf(x.x*inv); pk[1] = (short)f2bf(x.y*inv);
                pk[2] = (short)f2bf(x.z*inv); pk[3] = (short)f2bf(x.w*inv);
                pk[4] = (short)f2bf(y.x*inv); pk[5] = (short)f2bf(y.y*inv);
                pk[6] = (short)f2bf(y.z*inv); pk[7] = (short)f2bf(y.w*inv);
                *(short8*)(dst + h * 8) = pk;
            }
            if (c + 2 < nch) {                   // issue chunk c+2 loads
                const float4* src = qbase + (size_t)(c + 2) * 64 * 64;
                #pragma unroll
                for (int i = 0; i < 8; ++i) v[i] = src[i];
            }
        }

        // ---- compute chunk c from A[p]: two 32-row subtiles, acc reused ----
        #pragma unroll
        for (int st = 0; st < 2; ++st) {
            f32x16 acc0, acc1;
            #pragma unroll
            for (int r = 0; r < 16; ++r) { acc0[r] = 0.f; acc1[r] = 0.f; }
            const unsigned short* ab = &A[p][(st * 32 + lr) * LDP2 + lh * 8];
            __builtin_amdgcn_s_setprio(1);
            #pragma unroll
            for (int k = 0; k < 16; ++k) {
                short8 af = *(const short8*)(ab + k * 16);
                acc0 = __builtin_amdgcn_mfma_f32_32x32x16_bf16(af, b[k],      acc0, 0, 0, 0);
                acc1 = __builtin_amdgcn_mfma_f32_32x32x16_bf16(af, b[k + 16], acc1, 0, 0, 0);
            }
            __builtin_amdgcn_s_setprio(0);
            const int col = 64 * w + lr;
            const int rb  = m0 + c * 64 + st * 32 + 4 * lh;
            #pragma unroll
            for (int r = 0; r < 16; ++r) {
                int row = rb + (r & 3) + 8 * (r >> 2);
                __builtin_nontemporal_store(acc0[r], &out[(size_t)row * CC + col]);
                __builtin_nontemporal_store(acc1[r], &out[(size_t)row * CC + col + 32]);
            }
        }

        __builtin_amdgcn_sched_barrier(0);
        asm volatile("s_waitcnt lgkmcnt(0)");    // my ds_writes (stage) + ds_reads (af) retired
        __builtin_amdgcn_sched_barrier(0);
        __builtin_amdgcn_s_barrier();            // A[p^1] ready for all / A[p] reads done
        __builtin_amdgcn_sched_barrier(0);
    }
}

extern "C" void kernel_launch(void* const* d_in, const int* in_sizes, int n_in,
                              void* d_out, int out_size, void* d_ws, size_t ws_size,
                              hipStream_t stream) {
    const float* S      = (const float*)d_in[0];
    const int*   labels = (const int*)d_in[1];
    const float* Qf     = (const float*)d_in[2];
    const float* lscale = (const float*)d_in[3];
    const float* pshr   = (const float*)d_in[4];

    const int N_s = in_sizes[0] / DD;     // 65536
    const int N_q = in_sizes[2] / DD;     // 131072

    float* sums2         = (float*)d_ws;                                   // 2*512*256*4
    float* counts2       = (float*)((char*)d_ws + 1048576);                // 2*512*4
    float* gpart         = (float*)((char*)d_ws + 1052672);                // 8*256*4
    unsigned short* Pt   = (unsigned short*)((char*)d_ws + 1060864);       // 512*256*2

    float* out   = (float*)d_out;
    float* outUC = out + (size_t)N_q * CC;

    const int nblk = 256;
    const int nch  = N_q / (nblk * 64);   // 8 chunks of 64 rows per block

    class_sum_kernel<<<2 * CC, 256, 0, stream>>>((const f32x4*)S, labels, sums2, counts2, N_s);
    centroid_kernel<<<8, 256, 0, stream>>>(sums2, gpart);
    proto_kernel<<<CC, 256, 0, stream>>>(sums2, counts2, gpart, pshr, lscale, Pt, outUC, N_s);
    logits_kernel<<<nblk, 512, 0, stream>>>((const float4*)Qf, Pt, out, nch);
}

// Round 7
// 110.454 us; speedup vs baseline: 1.8257x; 1.0015x over previous
//
#include <hip/hip_runtime.h>

typedef __attribute__((ext_vector_type(4)))  float f32x4;
typedef __attribute__((ext_vector_type(16))) float f32x16;
typedef __attribute__((ext_vector_type(8)))  short short8;

#define DD 256          // feature dim
#define CC 512          // num classes
#define LDP2 264        // padded LDS row stride (bf16 elems): 528B

__device__ __forceinline__ unsigned short f2bf(float f) {
    union { float f; unsigned u; } x; x.f = f;
    unsigned r = x.u + 0x7FFFu + ((x.u >> 16) & 1u);   // RNE
    return (unsigned short)(r >> 16);
}

__device__ __forceinline__ f32x4 ntload4(const f32x4* p) {
    return __builtin_nontemporal_load(p);
}

// ---------------- K1: per-class segment sum of normalized support rows ----------------
__global__ __launch_bounds__(256) void class_sum_kernel(
    const f32x4* __restrict__ S, const int* __restrict__ labels,
    float* __restrict__ sums2, float* __restrict__ counts2, int N_s)
{
    const int c = blockIdx.x >> 1, half = blockIdx.x & 1;
    const int w = threadIdx.x >> 6, l = threadIdx.x & 63;
    const int seg  = N_s >> 3;
    const int base = half * (N_s >> 1) + w * seg;
    const int4* lab4 = (const int4*)(labels + base);
    const int iters = seg >> 8;

    float ax = 0.f, ay = 0.f, az = 0.f, aw = 0.f;
    int cnt = 0;

    int4 pf0 = lab4[l];
    int4 pf1 = (iters > 1) ? lab4[64 + l] : make_int4(-1, -1, -1, -1);

    for (int it = 0; it < iters; ++it) {
        int4 lv = pf0;
        pf0 = pf1;
        pf1 = (it + 2 < iters) ? lab4[(it + 2) * 64 + l] : make_int4(-1, -1, -1, -1);
        #pragma unroll
        for (int s = 0; s < 4; ++s) {
            int lab = (s == 0) ? lv.x : (s == 1) ? lv.y : (s == 2) ? lv.z : lv.w;
            unsigned long long m = __ballot(lab == c);
            cnt += __popcll(m);
            while (m) {
                int p0 = __ffsll((long long)m) - 1; m &= m - 1;
                int p1 = -1, p2 = -1, p3 = -1;
                if (m) { p1 = __ffsll((long long)m) - 1; m &= m - 1;
                    if (m) { p2 = __ffsll((long long)m) - 1; m &= m - 1;
                        if (m) { p3 = __ffsll((long long)m) - 1; m &= m - 1; } } }
                f32x4 v0 = ntload4(&S[(size_t)(base + (it * 64 + p0) * 4 + s) * 64 + l]);
                f32x4 v1 = {0,0,0,0}, v2 = {0,0,0,0}, v3 = {0,0,0,0};
                if (p1 >= 0) v1 = ntload4(&S[(size_t)(base + (it * 64 + p1) * 4 + s) * 64 + l]);
                if (p2 >= 0) v2 = ntload4(&S[(size_t)(base + (it * 64 + p2) * 4 + s) * 64 + l]);
                if (p3 >= 0) v3 = ntload4(&S[(size_t)(base + (it * 64 + p3) * 4 + s) * 64 + l]);
                float s0 = v0[0]*v0[0] + v0[1]*v0[1] + v0[2]*v0[2] + v0[3]*v0[3];
                float s1 = v1[0]*v1[0] + v1[1]*v1[1] + v1[2]*v1[2] + v1[3]*v1[3];
                float s2 = v2[0]*v2[0] + v2[1]*v2[1] + v2[2]*v2[2] + v2[3]*v2[3];
                float s3 = v3[0]*v3[0] + v3[1]*v3[1] + v3[2]*v3[2] + v3[3]*v3[3];
                #pragma unroll
                for (int off = 32; off; off >>= 1) {
                    s0 += __shfl_xor(s0, off);
                    s1 += __shfl_xor(s1, off);
                    s2 += __shfl_xor(s2, off);
                    s3 += __shfl_xor(s3, off);
                }
                float i0 = 1.0f / fmaxf(sqrtf(s0), 1e-8f);
                ax += v0[0]*i0; ay += v0[1]*i0; az += v0[2]*i0; aw += v0[3]*i0;
                if (p1 >= 0) { float i1 = 1.0f / fmaxf(sqrtf(s1), 1e-8f);
                    ax += v1[0]*i1; ay += v1[1]*i1; az += v1[2]*i1; aw += v1[3]*i1; }
                if (p2 >= 0) { float i2 = 1.0f / fmaxf(sqrtf(s2), 1e-8f);
                    ax += v2[0]*i2; ay += v2[1]*i2; az += v2[2]*i2; aw += v2[3]*i2; }
                if (p3 >= 0) { float i3 = 1.0f / fmaxf(sqrtf(s3), 1e-8f);
                    ax += v3[0]*i3; ay += v3[1]*i3; az += v3[2]*i3; aw += v3[3]*i3; }
            }
        }
    }

    __shared__ float lred[4][DD];
    __shared__ float lcnt[4];
    lred[w][4*l+0] = ax; lred[w][4*l+1] = ay; lred[w][4*l+2] = az; lred[w][4*l+3] = aw;
    if (l == 0) lcnt[w] = (float)cnt;
    __syncthreads();
    int t = threadIdx.x;
    sums2[(size_t)(half * CC + c) * DD + t] = lred[0][t] + lred[1][t] + lred[2][t] + lred[3][t];
    if (t == 0) counts2[half * CC + c] = lcnt[0] + lcnt[1] + lcnt[2] + lcnt[3];
}

// ---------------- K2: centroid partials (8 blocks, no atomics) ----------------
__global__ __launch_bounds__(256) void centroid_kernel(
    const float* __restrict__ sums2, float* __restrict__ gpart)
{
    const int d = threadIdx.x, b = blockIdx.x;
    float s = 0.f;
    for (int j = 0; j < 64; ++j) {
        int c = b * 64 + j;
        s += sums2[(size_t)c * DD + d] + sums2[(size_t)(CC + c) * DD + d];
    }
    gpart[b * DD + d] = s;
}

// ---------------- K3: prototypes -> bf16 Pt in MFMA B-frag layout, SCALE FOLDED IN ----
// Pt element for (class c, dim d):
//   CT=c>>5, KT=d>>4, lane=(c&31)+32*((d>>3)&1), e=d&7 -> Pt[((CT*16+KT)*64+lane)*8+e]
__global__ __launch_bounds__(256) void proto_kernel(
    const float* __restrict__ sums2, const float* __restrict__ counts2,
    const float* __restrict__ gpart, const float* __restrict__ proto_shrink,
    const float* __restrict__ logit_scale,
    unsigned short* __restrict__ Pt, float* __restrict__ outUC, int N_s)
{
    const int c = blockIdx.x, d = threadIdx.x;
    float ps = proto_shrink[0];
    float ab = 1.0f / (1.0f + __expf(-ps));
    ab = fminf(fmaxf(ab, 0.0f), 0.4f);
    const float sc = fminf(fmaxf(logit_scale[0], 1.0f), 100.0f);

    float sum  = sums2[(size_t)c * DD + d] + sums2[(size_t)(CC + c) * DD + d];
    float cntv = fmaxf(counts2[c] + counts2[CC + c], 1.0f);
    float g = 0.f;
    #pragma unroll
    for (int b = 0; b < 8; ++b) g += gpart[b * DD + d];
    g /= (float)N_s;

    float mean  = sum / cntv;
    float alpha = ab / sqrtf(cntv);
    float p = (1.0f - alpha) * mean + alpha * g;

    float ss = p * p;
    #pragma unroll
    for (int off = 32; off; off >>= 1) ss += __shfl_xor(ss, off);
    __shared__ float l4[4];
    if ((threadIdx.x & 63) == 0) l4[threadIdx.x >> 6] = ss;
    __syncthreads();
    ss = l4[0] + l4[1] + l4[2] + l4[3];
    float inv = sc / fmaxf(sqrtf(ss), 1e-8f);    // logit scale folded into prototype

    const int CT = c >> 5, KT = d >> 4;
    const int lane = (c & 31) + 32 * ((d >> 3) & 1);
    const int e = d & 7;
    Pt[(size_t)(((CT * 16 + KT) * 64 + lane)) * 8 + e] = f2bf(p * inv);
    if (d == 0) outUC[c] = (float)c;
}

// ---------------- K4: logits = normalize(q) @ (P*s)^T ----------------
// Persistent: grid 256 (1 block/CU), 1024 threads = 16 waves (4 waves/SIMD for 2x TLP).
// Wave w owns 32 output cols: b[16] = 64 VGPR -> total ~120 VGPR, capped at 128 by
// __launch_bounds__(1024,4). Q streams through double-buffered 64-row LDS chunks,
// single barrier per chunk; stage(c+1) co-scheduled with compute(c) (disjoint buffers).
__global__ __launch_bounds__(1024, 4) void logits_kernel(
    const float4* __restrict__ Q, const unsigned short* __restrict__ Pt,
    float* __restrict__ out, int nch)
{
    __shared__ unsigned short A[2][64 * LDP2];   // 2 x 33.8 KB

    const int t  = threadIdx.x;
    const int w  = t >> 6, l = t & 63;
    const int lr = l & 31, lh = l >> 5;
    const int m0 = blockIdx.x * nch * 64;        // this block's row range
    const int sr = t >> 4, sc = t & 15;          // staging: 16 threads/row, 16 floats each

    // ---- B prologue: wave w's 32 columns (tile w), frag-ready coalesced loads ----
    short8 b[16];
    #pragma unroll
    for (int k = 0; k < 16; ++k)
        b[k] = *(const short8*)(Pt + (size_t)((w * 16 + k) * 64 + l) * 8);

    const float4* qbase = Q + (size_t)(m0 + sr) * 64 + sc * 4;

    float4 v[4];
    #pragma unroll
    for (int i = 0; i < 4; ++i) v[i] = qbase[i];            // chunk 0 (64B contiguous)

    // stage chunk 0 -> A[0]
    {
        float ss = 0.f;
        #pragma unroll
        for (int i = 0; i < 4; ++i)
            ss += v[i].x*v[i].x + v[i].y*v[i].y + v[i].z*v[i].z + v[i].w*v[i].w;
        ss += __shfl_xor(ss, 1); ss += __shfl_xor(ss, 2);
        ss += __shfl_xor(ss, 4); ss += __shfl_xor(ss, 8);
        float inv = 1.0f / fmaxf(sqrtf(ss), 1e-8f);
        unsigned short* dst = &A[0][sr * LDP2 + sc * 16];
        #pragma unroll
        for (int h = 0; h < 2; ++h) {
            short8 pk;
            float4 x = v[2*h], y = v[2*h+1];
            pk[0] = (short)f2bf(x.x*inv); pk[1] = (short)f2bf(x.y*inv);
            pk[2] = (short)f2bf(x.z*inv); pk[3] = (short)f2bf(x.w*inv);
            pk[4] = (short)f2bf(y.x*inv); pk[5] = (short)f2bf(y.y*inv);
            pk[6] = (short)f2bf(y.z*inv); pk[7] = (short)f2bf(y.w*inv);
            *(short8*)(dst + h * 8) = pk;
        }
    }
    if (nch > 1) {                                          // chunk 1 loads in flight
        const float4* src = qbase + (size_t)64 * 64;
        #pragma unroll
        for (int i = 0; i < 4; ++i) v[i] = src[i];
    }
    __builtin_amdgcn_sched_barrier(0);
    asm volatile("s_waitcnt lgkmcnt(0)");
    __builtin_amdgcn_sched_barrier(0);
    __builtin_amdgcn_s_barrier();                // A[0] ready
    __builtin_amdgcn_sched_barrier(0);

    for (int c = 0; c < nch; ++c) {
        const int p = c & 1;

        // ---- stage chunk c+1 -> A[p^1] (same phase as compute; disjoint buffer) ----
        if (c + 1 < nch) {
            float ss = 0.f;
            #pragma unroll
            for (int i = 0; i < 4; ++i)
                ss += v[i].x*v[i].x + v[i].y*v[i].y + v[i].z*v[i].z + v[i].w*v[i].w;
            ss += __shfl_xor(ss, 1); ss += __shfl_xor(ss, 2);
            ss += __shfl_xor(ss, 4); ss += __shfl_xor(ss, 8);
            float inv = 1.0f / fmaxf(sqrtf(ss), 1e-8f);
            unsigned short* dst = &A[p ^ 1][sr * LDP2 + sc * 16];
            #pragma unroll
            for (int h = 0; h < 2; ++h) {
                short8 pk;
                float4 x = v[2*h], y = v[2*h+1];
                pk[0] = (short)f2bf(x.x*inv); pk[1] = (short)f2bf(x.y*inv);
                pk[2] = (short)f2bf(x.z*inv); pk[3] = (short)f2bf(x.w*inv);
                pk[4] = (short)f2bf(y.x*inv); pk[5] = (short)f2bf(y.y*inv);
                pk[6] = (short)f2bf(y.z*inv); pk[7] = (short)f2bf(y.w*inv);
                *(short8*)(dst + h * 8) = pk;
            }
            if (c + 2 < nch) {                   // issue chunk c+2 loads
                const float4* src = qbase + (size_t)(c + 2) * 64 * 64;
                #pragma unroll
                for (int i = 0; i < 4; ++i) v[i] = src[i];
            }
        }

        // ---- compute chunk c from A[p]: two 32-row subtiles, acc reused ----
        #pragma unroll
        for (int st = 0; st < 2; ++st) {
            f32x16 acc;
            #pragma unroll
            for (int r = 0; r < 16; ++r) acc[r] = 0.f;
            const unsigned short* ab = &A[p][(st * 32 + lr) * LDP2 + lh * 8];
            __builtin_amdgcn_s_setprio(1);
            #pragma unroll
            for (int k = 0; k < 16; ++k) {
                short8 af = *(const short8*)(ab + k * 16);
                acc = __builtin_amdgcn_mfma_f32_32x32x16_bf16(af, b[k], acc, 0, 0, 0);
            }
            __builtin_amdgcn_s_setprio(0);
            const int col = 32 * w + lr;
            const int rb  = m0 + c * 64 + st * 32 + 4 * lh;
            #pragma unroll
            for (int r = 0; r < 16; ++r) {
                int row = rb + (r & 3) + 8 * (r >> 2);
                __builtin_nontemporal_store(acc[r], &out[(size_t)row * CC + col]);
            }
        }

        __builtin_amdgcn_sched_barrier(0);
        asm volatile("s_waitcnt lgkmcnt(0)");    // my ds_writes (stage) + ds_reads (af) retired
        __builtin_amdgcn_sched_barrier(0);
        __builtin_amdgcn_s_barrier();            // A[p^1] ready for all / A[p] reads done
        __builtin_amdgcn_sched_barrier(0);
    }
}

extern "C" void kernel_launch(void* const* d_in, const int* in_sizes, int n_in,
                              void* d_out, int out_size, void* d_ws, size_t ws_size,
                              hipStream_t stream) {
    const float* S      = (const float*)d_in[0];
    const int*   labels = (const int*)d_in[1];
    const float* Qf     = (const float*)d_in[2];
    const float* lscale = (const float*)d_in[3];
    const float* pshr   = (const float*)d_in[4];

    const int N_s = in_sizes[0] / DD;     // 65536
    const int N_q = in_sizes[2] / DD;     // 131072

    float* sums2         = (float*)d_ws;                                   // 2*512*256*4
    float* counts2       = (float*)((char*)d_ws + 1048576);                // 2*512*4
    float* gpart         = (float*)((char*)d_ws + 1052672);                // 8*256*4
    unsigned short* Pt   = (unsigned short*)((char*)d_ws + 1060864);       // 512*256*2

    float* out   = (float*)d_out;
    float* outUC = out + (size_t)N_q * CC;

    const int nblk = 256;
    const int nch  = N_q / (nblk * 64);   // 8 chunks of 64 rows per block

    class_sum_kernel<<<2 * CC, 256, 0, stream>>>((const f32x4*)S, labels, sums2, counts2, N_s);
    centroid_kernel<<<8, 256, 0, stream>>>(sums2, gpart);
    proto_kernel<<<CC, 256, 0, stream>>>(sums2, counts2, gpart, pshr, lscale, Pt, outUC, N_s);
    logits_kernel<<<nblk, 1024, 0, stream>>>((const float4*)Qf, Pt, out, nch);
}